// Round 5
// baseline (678.634 us; speedup 1.0000x reference)
//
#include <hip/hip_runtime.h>

#define N_TOTAL 204800
#define NB 1024
#define DIM 512
#define NC 52
#define BN_EPS 1e-5f

typedef float nf4 __attribute__((ext_vector_type(4)));   // native vector: OK for nontemporal builtins

__device__ inline float bn_relu1(float v, int f,
                                 const float* __restrict__ s1, const float* __restrict__ s2,
                                 const float* __restrict__ g, const float* __restrict__ beta) {
    float m  = s1[f] * (1.0f / NB);
    float vv = s2[f] * (1.0f / NB) - m * m;
    float is = rsqrtf(vv + BN_EPS);
    float h  = g[f] * (v - m) * is + beta[f];
    return h > 0.f ? h : 0.f;
}

// ---------------- K1: segment-mean pooling, self-computed offsets ----------
// grid (NB, 4), 256 threads. Each block: 32 float4 columns (512 B/row) of one
// graph. Counts buffer is L1/L2-resident; each block sums counts[j<g] itself.
// z is a 419 MB single-pass stream -> nontemporal loads (no L2/L3 pollution).
// Also zero-inits BN stats and the grid-barrier words for k_mlp.
__global__ __launch_bounds__(256) void k_pool(const float* __restrict__ z,
                                              const int* __restrict__ bnn,
                                              float* __restrict__ stats,
                                              unsigned* __restrict__ bar,
                                              float* __restrict__ X) {
    __shared__ nf4 buf[3][32];
    __shared__ int redA[4], redB[4];
    int g   = blockIdx.x;
    int cc  = blockIdx.y;              // column chunk 0..3
    int tid = threadIdx.x;
    int lane = tid & 63;
    int w    = tid >> 6;               // wave 0..3

    // ---- pass 1: total of raw int32 words -> dtype detect ----
    int t_all = 0;
#pragma unroll
    for (int k = 0; k < 4; k++) t_all += bnn[tid + k * 256];
#pragma unroll
    for (int s = 1; s < 64; s <<= 1) t_all += __shfl_xor(t_all, s);
    if (lane == 0) redA[w] = t_all;
    __syncthreads();
    bool is64 = (redA[0] + redA[1] + redA[2] + redA[3]) != N_TOTAL;

    // ---- pass 2: exclusive prefix (sum of counts j < g) ----
    int t_pre = 0;
#pragma unroll
    for (int k = 0; k < 4; k++) {
        int j = tid + k * 256;
        if (j < g) t_pre += is64 ? bnn[2 * j] : bnn[j];
    }
#pragma unroll
    for (int s = 1; s < 64; s <<= 1) t_pre += __shfl_xor(t_pre, s);
    if (lane == 0) redB[w] = t_pre;
    // zero BN stats (2048 floats) + barrier words; pool completes before
    // k_mlp launches (stream order), so these are initialized in time.
    if (cc == 0 && g < 8) stats[g * 256 + tid] = 0.0f;
    if (cc == 0 && g == 8 && tid < 4) bar[tid] = 0u;
    __syncthreads();
    int s0 = redB[0] + redB[1] + redB[2] + redB[3];
    int n  = is64 ? bnn[2 * g] : bnn[g];
    float r = 1.0f / (float)n;

    // ---- streaming accumulation ----
    int c4 = tid & 31;                 // float4 column within chunk
    int rp = tid >> 5;                 // row phase 0..7
    const nf4* p = (const nf4*)z + (size_t)s0 * 128 + cc * 32 + c4;
    nf4 a0 = {0,0,0,0}, a1 = {0,0,0,0}, a2 = {0,0,0,0}, a3 = {0,0,0,0};
    int i = rp;
    for (; i + 56 < n; i += 64) {      // 8 loads in flight, rows stride 8
        nf4 v0 = __builtin_nontemporal_load(&p[(size_t)(i +  0) * 128]);
        nf4 v1 = __builtin_nontemporal_load(&p[(size_t)(i +  8) * 128]);
        nf4 v2 = __builtin_nontemporal_load(&p[(size_t)(i + 16) * 128]);
        nf4 v3 = __builtin_nontemporal_load(&p[(size_t)(i + 24) * 128]);
        nf4 v4 = __builtin_nontemporal_load(&p[(size_t)(i + 32) * 128]);
        nf4 v5 = __builtin_nontemporal_load(&p[(size_t)(i + 40) * 128]);
        nf4 v6 = __builtin_nontemporal_load(&p[(size_t)(i + 48) * 128]);
        nf4 v7 = __builtin_nontemporal_load(&p[(size_t)(i + 56) * 128]);
        a0 += v0; a1 += v1; a2 += v2; a3 += v3;
        a0 += v4; a1 += v5; a2 += v6; a3 += v7;
    }
    for (; i < n; i += 8) {
        a0 += __builtin_nontemporal_load(&p[(size_t)i * 128]);
    }
    a0 += a1; a2 += a3; a0 += a2;
    // merge rp pairs within each wave: lane^32 holds rp^1, same c4
    a0.x += __shfl_xor(a0.x, 32); a0.y += __shfl_xor(a0.y, 32);
    a0.z += __shfl_xor(a0.z, 32); a0.w += __shfl_xor(a0.w, 32);
    if (w > 0 && lane < 32) buf[w - 1][c4] = a0;
    __syncthreads();
    if (w == 0 && lane < 32) {
        a0 += buf[0][c4]; a0 += buf[1][c4]; a0 += buf[2][c4];
        a0 *= r;
        ((nf4*)X)[(size_t)g * 128 + cc * 32 + c4] = a0;
    }
}

// ---------------- fused MLP: gemm1 | bar | gemm2 | bar | gemm3 -------------
// grid 256 blocks x 256 threads: one block per CU guaranteed co-resident
// (grid <= CU count, resources far under limits) -> device barrier is safe.

__device__ inline void grid_barrier(unsigned* cnt, unsigned* gen) {
    __threadfence();                       // make phase writes agent-visible
    __syncthreads();
    if (threadIdx.x == 0) {
        unsigned g = atomicAdd(gen, 0u);   // atomic load, device scope
        unsigned old = atomicAdd(cnt, 1u);
        if (old == 255u) {                 // last arriver
            atomicExch(cnt, 0u);           // reset before release
            atomicAdd(gen, 1u);
        } else {
            while (atomicAdd(gen, 0u) == g) { }
        }
    }
    __syncthreads();
    __threadfence();                       // acquire side
}

// 32x64 tile, 256 threads, acc 2x4 (VALU-bound inner loop: per CU-k
// ~1.15 KB LDS (9 clk) vs 16 clk FMA). Block b: row tile b>>3, col tile b&7.
template <bool BNA>
__device__ void gemm_phase(const float* __restrict__ A,
                           const float* __restrict__ W,
                           const float* __restrict__ bias,
                           const float* __restrict__ ps1,
                           const float* __restrict__ ps2,
                           const float* __restrict__ gam,
                           const float* __restrict__ bet,
                           float* __restrict__ Y,
                           float* __restrict__ os1,
                           float* __restrict__ os2,
                           float (&As)[32][34], float (&Ws)[32][68]) {
    int tid = threadIdx.x;
    int tx = tid & 15, ty = tid >> 4;
    int gr0 = (blockIdx.x >> 3) * 32;
    int gc0 = (blockIdx.x & 7) * 64;

    // A-staging: 256 float4 = 32 rows x 8 k-quads
    int arow = tid >> 3;          // 0..31
    int akq  = tid & 7;           // 0..7
    // W-staging: 512 float4 = 32 k x 16 col-quads, 2 per thread
    int wk0 = tid >> 4;           // 0..15
    int wcq = tid & 15;           // 0..15

    float acc[2][4] = {};

    float4 ra  = *(const float4*)&A[(size_t)(gr0 + arow) * DIM + akq * 4];
    float4 rw0 = *(const float4*)&W[(size_t)wk0 * DIM + gc0 + wcq * 4];
    float4 rw1 = *(const float4*)&W[(size_t)(wk0 + 16) * DIM + gc0 + wcq * 4];

    for (int kt = 0; kt < 16; kt++) {
        float4 v = ra;
        if (BNA) {
            int f0 = kt * 32 + akq * 4;
            v.x = bn_relu1(v.x, f0 + 0, ps1, ps2, gam, bet);
            v.y = bn_relu1(v.y, f0 + 1, ps1, ps2, gam, bet);
            v.z = bn_relu1(v.z, f0 + 2, ps1, ps2, gam, bet);
            v.w = bn_relu1(v.w, f0 + 3, ps1, ps2, gam, bet);
        }
        As[akq * 4 + 0][arow] = v.x;
        As[akq * 4 + 1][arow] = v.y;
        As[akq * 4 + 2][arow] = v.z;
        As[akq * 4 + 3][arow] = v.w;
        *(float4*)&Ws[wk0][wcq * 4]      = rw0;
        *(float4*)&Ws[wk0 + 16][wcq * 4] = rw1;
        __syncthreads();

        if (kt < 15) {
            int k0 = (kt + 1) * 32;
            ra  = *(const float4*)&A[(size_t)(gr0 + arow) * DIM + k0 + akq * 4];
            rw0 = *(const float4*)&W[(size_t)(k0 + wk0) * DIM + gc0 + wcq * 4];
            rw1 = *(const float4*)&W[(size_t)(k0 + wk0 + 16) * DIM + gc0 + wcq * 4];
        }

#pragma unroll
        for (int k = 0; k < 32; k++) {
            float2 a = *(const float2*)&As[k][ty * 2];
            float4 w = *(const float4*)&Ws[k][tx * 4];
            acc[0][0] += a.x * w.x; acc[0][1] += a.x * w.y;
            acc[0][2] += a.x * w.z; acc[0][3] += a.x * w.w;
            acc[1][0] += a.y * w.x; acc[1][1] += a.y * w.y;
            acc[1][2] += a.y * w.z; acc[1][3] += a.y * w.w;
        }
        __syncthreads();
    }

    // epilogue: +bias, store, column stats (wave-reduced, then atomics)
    float4 b = *(const float4*)&bias[gc0 + tx * 4];
    float s[4] = {}, q[4] = {};
#pragma unroll
    for (int i = 0; i < 2; i++) {
        float4 y;
        y.x = acc[i][0] + b.x;
        y.y = acc[i][1] + b.y;
        y.z = acc[i][2] + b.z;
        y.w = acc[i][3] + b.w;
        *(float4*)&Y[(size_t)(gr0 + ty * 2 + i) * DIM + gc0 + tx * 4] = y;
        s[0] += y.x; q[0] += y.x * y.x;
        s[1] += y.y; q[1] += y.y * y.y;
        s[2] += y.z; q[2] += y.z * y.z;
        s[3] += y.w; q[3] += y.w * y.w;
    }
    // reduce across the 4 ty values within each wave (lanes differ by 16, 32)
#pragma unroll
    for (int j = 0; j < 4; j++) {
        s[j] += __shfl_xor(s[j], 16); s[j] += __shfl_xor(s[j], 32);
        q[j] += __shfl_xor(q[j], 16); q[j] += __shfl_xor(q[j], 32);
    }
    if ((ty & 3) == 0) {
#pragma unroll
        for (int j = 0; j < 4; j++) {
            atomicAdd(&os1[gc0 + tx * 4 + j], s[j]);
            atomicAdd(&os2[gc0 + tx * 4 + j], q[j]);
        }
    }
}

__global__ __launch_bounds__(256) void k_mlp(const float* __restrict__ X,
                                             const float* __restrict__ w1,
                                             const float* __restrict__ b1,
                                             const float* __restrict__ g1,
                                             const float* __restrict__ be1,
                                             const float* __restrict__ w2,
                                             const float* __restrict__ b2,
                                             const float* __restrict__ g2,
                                             const float* __restrict__ be2,
                                             const float* __restrict__ w3,
                                             const float* __restrict__ b3,
                                             float* __restrict__ stats,
                                             unsigned* __restrict__ bar,
                                             float* __restrict__ Y1,
                                             float* __restrict__ Y2,
                                             float* __restrict__ out) {
    __shared__ float As[32][34];
    __shared__ float Ws[32][68];
    __shared__ float A3[4][DIM];

    // phase 1: Y1 = X @ w1 + b1; stats -> s1a,s2a
    gemm_phase<false>(X, w1, b1, nullptr, nullptr, nullptr, nullptr,
                      Y1, stats, stats + 512, As, Ws);
    grid_barrier(bar, bar + 1);

    // phase 2: Y2 = BN1ReLU(Y1) @ w2 + b2; stats -> s1b,s2b
    gemm_phase<true>(Y1, w2, b2, stats, stats + 512, g1, be1,
                     Y2, stats + 1024, stats + 1536, As, Ws);
    grid_barrier(bar, bar + 1);

    // phase 3: out = BN2ReLU(Y2) @ w3 + b3  (4 rows per block)
    int tid = threadIdx.x;
    int r0 = blockIdx.x * 4;
    const float* s1 = stats + 1024;
    const float* s2 = stats + 1536;
#pragma unroll
    for (int it = 0; it < 2; it++) {
        int idx = it * 256 + tid;
        int row = idx >> 7;
        int cq  = idx & 127;
        int f   = cq * 4;
        float4 v = *(const float4*)&Y2[(size_t)(r0 + row) * DIM + f];
        v.x = bn_relu1(v.x, f + 0, s1, s2, g2, be2);
        v.y = bn_relu1(v.y, f + 1, s1, s2, g2, be2);
        v.z = bn_relu1(v.z, f + 2, s1, s2, g2, be2);
        v.w = bn_relu1(v.w, f + 3, s1, s2, g2, be2);
        *(float4*)&A3[row][f] = v;
    }
    __syncthreads();
    int col = tid & 63;
    int row = tid >> 6;
    if (col < NC) {
        float acc = 0.f;
#pragma unroll 8
        for (int k = 0; k < DIM; k += 4) {
            float4 a = *(const float4*)&A3[row][k];
            acc += a.x * w3[(size_t)(k + 0) * NC + col];
            acc += a.y * w3[(size_t)(k + 1) * NC + col];
            acc += a.z * w3[(size_t)(k + 2) * NC + col];
            acc += a.w * w3[(size_t)(k + 3) * NC + col];
        }
        out[(size_t)(r0 + row) * NC + col] = acc + b3[col];
    }
}

extern "C" void kernel_launch(void* const* d_in, const int* in_sizes, int n_in,
                              void* d_out, int out_size, void* d_ws, size_t ws_size,
                              hipStream_t stream) {
    const float* z   = (const float*)d_in[0];
    const int*   bnn = (const int*)d_in[1];
    const float* w1  = (const float*)d_in[2];
    const float* b1  = (const float*)d_in[3];
    const float* g1  = (const float*)d_in[4];
    const float* be1 = (const float*)d_in[5];
    const float* w2  = (const float*)d_in[6];
    const float* b2  = (const float*)d_in[7];
    const float* g2  = (const float*)d_in[8];
    const float* be2 = (const float*)d_in[9];
    const float* w3  = (const float*)d_in[10];
    const float* b3  = (const float*)d_in[11];

    float*    stats = (float*)d_ws;            // 2048 floats: s1a|s2a|s1b|s2b
    unsigned* bar   = (unsigned*)(stats + 2048); // 4 u32 (cnt, gen, pad)
    float*    X     = stats + 2048 + 4;        // 16B-aligned (offset 8208 % 16 == 0)
    float*    Y1    = X  + (size_t)NB * DIM;
    float*    Y2    = Y1 + (size_t)NB * DIM;
    float*    out   = (float*)d_out;

    k_pool<<<dim3(NB, 4), 256, 0, stream>>>(z, bnn, stats, bar, X);

    k_mlp<<<256, 256, 0, stream>>>(X, w1, b1, g1, be1, w2, b2, g2, be2,
                                   w3, b3, stats, bar, Y1, Y2, out);
}